// Round 1
// baseline (69.419 us; speedup 1.0000x reference)
//
#include <hip/hip_runtime.h>
#include <math.h>

// Problem constants (match reference)
#define B_      16
#define T_      2048
#define NFREQ_  1152
#define NOCT_   9
#define NFB_    128          // base freqs per octave
#define EPS_    1e-4f
#define NCH_    16           // t-chunks per batch (grid y)
#define CT_     (T_ / NCH_)  // 128 t per block
#define QT_     (CT_ / 4)    // 32 t per quarter (block = 4 quarters x 128 lanes)

// Main kernel: for each (b, t-chunk), lane = base frequency (one octave),
// 9 octaves derived by exact angle doubling. Accumulate p1/p2 into global
// acc[b][2][1152] via atomics (each slot gets 16 adds).
__global__ __launch_bounds__(512) void spectral_main(
    const float* __restrict__ batch, const float* __restrict__ freqs,
    float* __restrict__ acc)
{
  const int b      = blockIdx.x;
  const int ch     = blockIdx.y;
  const int tid    = threadIdx.x;
  const int lane_f = tid & 127;
  const int q      = tid >> 7;
  const int t0     = ch * CT_;

  const float* ts = batch + (size_t)b * 2 * T_;
  const float* ys = ts + T_;

  __shared__ float r1[512], r2[512];
  __shared__ float lds_ts[CT_], lds_y[CT_];
  __shared__ float comb[3 * 128 * 18];   // quarters 1..3 partials

  // --- per-batch stats of ys (redundant per block; trivial cost, L2-hit) ---
  float lsum = 0.f, lsq = 0.f;
#pragma unroll
  for (int k = 0; k < T_ / 512; ++k) {
    float v = ys[tid + k * 512];
    lsum += v; lsq = fmaf(v, v, lsq);
  }
  // stage this block's chunk while stats are in flight
  if (tid < CT_)            lds_ts[tid]       = ts[t0 + tid];
  else if (tid < 2 * CT_)   lds_y[tid - CT_]  = ys[t0 + tid - CT_];
  r1[tid] = lsum; r2[tid] = lsq;
  __syncthreads();
  for (int off = 256; off > 0; off >>= 1) {
    if (tid < off) { r1[tid] += r1[tid + off]; r2[tid] += r2[tid + off]; }
    __syncthreads();
  }
  float mean  = r1[0] * (1.f / T_);
  float var   = (r2[0] - (float)T_ * mean * mean) * (1.f / (T_ - 1));
  float inv_s = 1.f / (sqrtf(fmaxf(var, 0.f)) + EPS_);
  if (tid < CT_) lds_y[tid] = (lds_y[tid] - mean) * inv_s;
  __syncthreads();

  // --- main loop: 1 sincos per t, octave doubling for the other 8 ---
  const float fr = freqs[lane_f];  // base-octave frequency (cycles per unit)
  float p1[NOCT_], p2[NOCT_];
#pragma unroll
  for (int o = 0; o < NOCT_; ++o) { p1[o] = 0.f; p2[o] = 0.f; }

  const int tb = q * QT_;
#pragma unroll 2
  for (int i = 0; i < QT_; ++i) {
    float z = lds_ts[tb + i];   // wave-uniform broadcast
    float y = lds_y[tb + i];
    float rev = z * fr;                         // revolutions = ts * f
    float rf  = rev - floorf(rev);              // range-reduce to [0,1)
    float s = __builtin_amdgcn_sinf(rf);        // v_sin_f32: sin(2*pi*rf)
    float c = __builtin_amdgcn_cosf(rf);
#pragma unroll
    for (int o = 0; o < NOCT_; ++o) {
      p1[o] = fmaf(y, s, p1[o]);
      p2[o] = fmaf(y, c, p2[o]);
      if (o < NOCT_ - 1) {
        float sc = s * c;
        c = fmaf(2.f * c, c, -1.f);             // cos(2x) = 2c^2 - 1
        s = sc + sc;                            // sin(2x) = 2sc
      }
    }
  }

  // --- combine the 4 quarters in LDS, quarter 0 does the atomics ---
  if (q > 0) {
    int base = ((q - 1) * 128 + lane_f) * 18;
#pragma unroll
    for (int o = 0; o < NOCT_; ++o) {
      comb[base + o]     = p1[o];
      comb[base + 9 + o] = p2[o];
    }
  }
  __syncthreads();
  if (q == 0) {
    float* accb = acc + (size_t)b * 2 * NFREQ_;
#pragma unroll
    for (int o = 0; o < NOCT_; ++o) {
      float v1 = p1[o], v2 = p2[o];
#pragma unroll
      for (int k = 0; k < 3; ++k) {
        int base = (k * 128 + lane_f) * 18;
        v1 += comb[base + o];
        v2 += comb[base + 9 + o];
      }
      atomicAdd(accb + o * 128 + lane_f,          v1);
      atomicAdd(accb + NFREQ_ + o * 128 + lane_f, v2);
    }
  }
}

// Finalize: mag = sqrt(p1^2+p2^2), tnorm over the 1152 freqs (ddof=1).
__global__ __launch_bounds__(256) void spectral_final(
    const float* __restrict__ acc, float* __restrict__ out)
{
  const int b   = blockIdx.x;
  const int tid = threadIdx.x;
  __shared__ float mag[NFREQ_];
  __shared__ float r1[256], r2[256];
  const float* accb = acc + (size_t)b * 2 * NFREQ_;

  float lsum = 0.f, lsq = 0.f;
  for (int f = tid; f < NFREQ_; f += 256) {
    float a = accb[f], c = accb[NFREQ_ + f];
    float m = sqrtf(fmaf(a, a, c * c));
    mag[f] = m;
    lsum += m; lsq = fmaf(m, m, lsq);
  }
  r1[tid] = lsum; r2[tid] = lsq;
  __syncthreads();
  for (int off = 128; off > 0; off >>= 1) {
    if (tid < off) { r1[tid] += r1[tid + off]; r2[tid] += r2[tid + off]; }
    __syncthreads();
  }
  float mean = r1[0] * (1.f / NFREQ_);
  float var  = (r2[0] - (float)NFREQ_ * mean * mean) * (1.f / (NFREQ_ - 1));
  float inv  = 1.f / (sqrtf(fmaxf(var, 0.f)) + EPS_);
  for (int f = tid; f < NFREQ_; f += 256)
    out[(size_t)b * NFREQ_ + f] = (mag[f] - mean) * inv;
}

extern "C" void kernel_launch(void* const* d_in, const int* in_sizes, int n_in,
                              void* d_out, int out_size, void* d_ws, size_t ws_size,
                              hipStream_t stream) {
  const float* batch = (const float*)d_in[0];   // (16, 2, 2048) f32
  const float* freqs = (const float*)d_in[1];   // (1152,) f32
  float* out = (float*)d_out;                   // (16, 1, 1152) f32
  float* acc = (float*)d_ws;                    // [16][2][1152] f32 = 147456 B

  // ws is re-poisoned to 0xAA before every timed launch — zero our accumulator.
  hipMemsetAsync(acc, 0, (size_t)B_ * 2 * NFREQ_ * sizeof(float), stream);
  spectral_main<<<dim3(B_, NCH_), 512, 0, stream>>>(batch, freqs, acc);
  spectral_final<<<B_, 256, 0, stream>>>(acc, out);
}